// Round 4
// baseline (11402.902 us; speedup 1.0000x reference)
//
#include <hip/hip_runtime.h>
#include <stdint.h>
#include <math.h>

#define NW      4096
#define TSTEPS  5722     // BURNIN + (512-1)*11 + 1
#define BURN    100
#define SSTRIDE 11
#define CH      1024
#define NTHR    256      // init threads; main loop = first wave only

struct K2 { uint32_t a, b; };

// Threefry-2x32, 20 rounds — matches jax._src.prng.threefry2x32 exactly.
__device__ __forceinline__ K2 tf(uint32_t k0, uint32_t k1, uint32_t c0, uint32_t c1) {
  uint32_t ks2 = k0 ^ k1 ^ 0x1BD11BDAu;
  uint32_t x0 = c0 + k0, x1 = c1 + k1;
#define RR(r) { x0 += x1; x1 = (x1 << (r)) | (x1 >> (32 - (r))); x1 ^= x0; }
  RR(13) RR(15) RR(26) RR(6)
  x0 += k1;  x1 += ks2 + 1u;
  RR(17) RR(29) RR(16) RR(24)
  x0 += ks2; x1 += k0 + 2u;
  RR(13) RR(15) RR(26) RR(6)
  x0 += k0;  x1 += k1 + 3u;
  RR(17) RR(29) RR(16) RR(24)
  x0 += k1;  x1 += ks2 + 4u;
  RR(13) RR(15) RR(26) RR(6)
  x0 += ks2; x1 += k0 + 5u;
#undef RR
  K2 r; r.a = x0; r.b = x1; return r;
}

__device__ __forceinline__ uint32_t xbits(K2 k) {
  K2 r = tf(k.a, k.b, 0u, 0u);
  return r.a ^ r.b;
}

__device__ __forceinline__ uint32_t ri_off(K2 key, uint32_t span) {
  K2 k1 = tf(key.a, key.b, 0u, 0u);
  K2 k2 = tf(key.a, key.b, 0u, 1u);
  uint32_t hb = xbits(k1);
  uint32_t lb = xbits(k2);
  uint32_t m = 65536u % span;
  m = (m * m) % span;
  return ((hb % span) * m + (lb % span)) % span;
}

__device__ __forceinline__ void make_prop(uint32_t kca, uint32_t kcb, int t,
                                          uint32_t& lohi, uint32_t& shv, float& lg) {
  K2 kt = tf(kca, kcb, 0u, (uint32_t)t);
  K2 kl = tf(kt.a, kt.b, 0u, 0u);
  K2 ka = tf(kt.a, kt.b, 0u, 1u);
  K2 kr = tf(kt.a, kt.b, 0u, 2u);
  K2 ku = tf(kt.a, kt.b, 0u, 3u);
  uint32_t l = 1u + ri_off(kl, 4095u);
  uint32_t a = ri_off(ka, 4097u - l);
  uint32_t b = a + l;
  uint32_t r = ri_off(kr, 4096u - l);
  uint32_t c = (b + r + 1u) % 4097u;
  uint32_t lo, hi, sh;
  if (a < c) { lo = a; hi = c; sh = b - a; }
  else       { lo = c; hi = b; sh = a - c; }
  uint32_t ub = xbits(ku);
  float uf = __uint_as_float((ub >> 9) | 0x3F800000u) - 1.0f;
  lohi = lo | (hi << 16);
  shv  = sh;
  lg   = (float)log((double)uf);
}

// smap: post-rotation source map. hi = lo + span. One unsigned compare covers both bounds.
__device__ __forceinline__ uint32_t smap2(uint32_t i, uint32_t lo, uint32_t span, uint32_t sh) {
  uint32_t t = i - lo;              // wraps huge if i < lo
  uint32_t u = t + sh;
  u = (u >= span) ? u - span : u;   // valid only when t < span
  return (t < span) ? lo + u : i;
}

// grid-parallel proposal precompute -> d_ws (16B records)
__global__ void prop_kernel(uint4* __restrict__ gprop) {
  int t = blockIdx.x * 256 + threadIdx.x;
  if (t >= TSTEPS) return;
  K2 kchain = tf(0u, 42u, 0u, 1u);
  uint32_t lohi, shv; float lg;
  make_prop(kchain.a, kchain.b, t, lohi, shv, lg);
  gprop[t] = make_uint4(lohi, shv, __float_as_uint(lg), 0u);
}

__device__ __forceinline__ void issue6(float (&dst)[6],
    uint32_t Q0, uint32_t Q1, uint32_t Q2, uint32_t Q3, uint32_t Q4, uint32_t Q5,
    uint32_t lo2, uint32_t hi2,
    const float* __restrict__ bigram, const float* __restrict__ startw,
    const float* __restrict__ endw) {
  // pl=Q0, pls=Q1, pls1=Q2, ph1=Q3, pm1=Q4, ph=Q5
  dst[0] = bigram[(size_t)Q3 * NW + Q0];
  dst[1] = bigram[(size_t)Q2 * NW + Q1];
  dst[2] = (lo2 > 0u)           ? bigram[(size_t)Q4 * NW + Q1] : startw[Q1];
  dst[3] = (lo2 > 0u)           ? bigram[(size_t)Q4 * NW + Q0] : startw[Q0];
  dst[4] = (hi2 < (uint32_t)NW) ? bigram[(size_t)Q2 * NW + Q5] : endw[Q2];
  dst[5] = (hi2 < (uint32_t)NW) ? bigram[(size_t)Q3 * NW + Q5] : endw[Q3];
}

// Consumes VR/VA (loads issued 2 steps ago, same-parity buffer) and refills
// them in place with speculative loads for step T+2.
__device__ __forceinline__ void step_body(
    int T, int TT, uint32_t lane, bool& accp,
    uint32_t (&Plo)[4], uint32_t (&Phi)[4], uint32_t (&Psh)[4], float (&Plg)[4],
    float (&VR)[6], float (&VA)[6],
    uint32_t* s_perm, const uint32_t* s_plohi, const uint32_t* s_psh, const float* s_plg,
    const float* __restrict__ bigram, const float* __restrict__ startw,
    const float* __restrict__ endw, int* __restrict__ out) {

  // ---- positions from proposal t+2 (slot 2) ----
  uint32_t lo2 = Plo[2], hi2 = Phi[2], sh2 = Psh[2];
  uint32_t g0 = lo2, g1 = lo2 + sh2, g2 = g1 - 1u, g3 = hi2 - 1u;
  uint32_t g4 = (lo2 > 0u) ? lo2 - 1u : 0u;
  uint32_t g5 = (hi2 < (uint32_t)NW) ? hi2 : 0u;

  // ---- inner smap (proposal t+1, slot 1) ----
  uint32_t lo1 = Plo[1], sp1 = Phi[1] - Plo[1], sh1 = Psh[1];
  uint32_t y0 = smap2(g0, lo1, sp1, sh1), y1 = smap2(g1, lo1, sp1, sh1);
  uint32_t y2 = smap2(g2, lo1, sp1, sh1), y3 = smap2(g3, lo1, sp1, sh1);
  uint32_t y4 = smap2(g4, lo1, sp1, sh1), y5 = smap2(g5, lo1, sp1, sh1);

  // ---- outer smap (proposal t, slot 0) — both acc_t variants ----
  uint32_t lo0 = Plo[0], sp0 = Phi[0] - Plo[0], sh0 = Psh[0];
  uint32_t zA0 = smap2(g0, lo0, sp0, sh0), zA1 = smap2(g1, lo0, sp0, sh0);
  uint32_t zA2 = smap2(g2, lo0, sp0, sh0), zA3 = smap2(g3, lo0, sp0, sh0);
  uint32_t zA4 = smap2(g4, lo0, sp0, sh0), zA5 = smap2(g5, lo0, sp0, sh0);
  uint32_t zB0 = smap2(y0, lo0, sp0, sh0), zB1 = smap2(y1, lo0, sp0, sh0);
  uint32_t zB2 = smap2(y2, lo0, sp0, sh0), zB3 = smap2(y3, lo0, sp0, sh0);
  uint32_t zB4 = smap2(y4, lo0, sp0, sh0), zB5 = smap2(y5, lo0, sp0, sh0);

  // ---- 24 LDS broadcast reads of P_t (pre-rotation state) ----
  uint32_t PR0 = s_perm[g0],  PR1 = s_perm[g1],  PR2 = s_perm[g2];
  uint32_t PR3 = s_perm[g3],  PR4 = s_perm[g4],  PR5 = s_perm[g5];
  uint32_t PB0 = s_perm[y0],  PB1 = s_perm[y1],  PB2 = s_perm[y2];
  uint32_t PB3 = s_perm[y3],  PB4 = s_perm[y4],  PB5 = s_perm[y5];
  uint32_t PA0 = s_perm[zA0], PA1 = s_perm[zA1], PA2 = s_perm[zA2];
  uint32_t PA3 = s_perm[zA3], PA4 = s_perm[zA4], PA5 = s_perm[zA5];
  uint32_t PC0 = s_perm[zB0], PC1 = s_perm[zB1], PC2 = s_perm[zB2];
  uint32_t PC3 = s_perm[zB3], PC4 = s_perm[zB4], PC5 = s_perm[zB5];

  // ---- prefetch proposal t+3 into slot 3 (uniform) ----
  {
    uint32_t lh = __builtin_amdgcn_readfirstlane(s_plohi[TT + 3]);
    Plo[3] = lh & 0xFFFFu; Phi[3] = lh >> 16;
    Psh[3] = __builtin_amdgcn_readfirstlane(s_psh[TT + 3]);
    Plg[3] = __uint_as_float(__builtin_amdgcn_readfirstlane(__float_as_uint(s_plg[TT + 3])));
  }

  // ---- decision t (vmcnt wait on 2-step-old loads lands here) ----
  float u0 = accp ? VA[0] : VR[0];
  float u1 = accp ? VA[1] : VR[1];
  float u2 = accp ? VA[2] : VR[2];
  float u3 = accp ? VA[3] : VR[3];
  float u4 = accp ? VA[4] : VR[4];
  float u5 = accp ? VA[5] : VR[5];
  double d = ((double)u0 - (double)u1) + ((double)u2 - (double)u3) + ((double)u4 - (double)u5);
  double mind = d < 0.0 ? d : 0.0;
  bool acc = mind > (double)Plg[0];
  int uacc = __builtin_amdgcn_readfirstlane((int)acc);

  // ---- select perm values, refill THIS buffer with loads for step t+2 ----
  uint32_t QR0 = uacc ? PA0 : PR0, QR1 = uacc ? PA1 : PR1, QR2 = uacc ? PA2 : PR2;
  uint32_t QR3 = uacc ? PA3 : PR3, QR4 = uacc ? PA4 : PR4, QR5 = uacc ? PA5 : PR5;
  uint32_t QA0 = uacc ? PC0 : PB0, QA1 = uacc ? PC1 : PB1, QA2 = uacc ? PC2 : PB2;
  uint32_t QA3 = uacc ? PC3 : PB3, QA4 = uacc ? PC4 : PB4, QA5 = uacc ? PC5 : PB5;
  issue6(VR, QR0, QR1, QR2, QR3, QR4, QR5, lo2, hi2, bigram, startw, endw);
  issue6(VA, QA0, QA1, QA2, QA3, QA4, QA5, lo2, hi2, bigram, startw, endw);

  // ---- rotation (uniform branch) ----
  if (uacc) {
    uint32_t rv[64];
    #pragma unroll
    for (int kb = 0; kb < 8; ++kb) {
      if ((uint32_t)(kb * 512) >= sp0) break;     // uniform early-out
      #pragma unroll
      for (int kk = 0; kk < 8; ++kk) {
        int k = kb * 8 + kk;
        uint32_t e = lane + (uint32_t)k * 64u;
        uint32_t s = e + sh0; s = (s >= sp0) ? s - sp0 : s;
        uint32_t addr = (e < sp0) ? lo0 + s : 0u;  // clamp, value discarded
        rv[k] = s_perm[addr];
      }
    }
    __builtin_amdgcn_sched_barrier(0);
    #pragma unroll
    for (int kb = 0; kb < 8; ++kb) {
      if ((uint32_t)(kb * 512) >= sp0) break;
      #pragma unroll
      for (int kk = 0; kk < 8; ++kk) {
        int k = kb * 8 + kk;
        uint32_t e = lane + (uint32_t)k * 64u;
        uint32_t addrw = (e < sp0) ? lo0 + e : (uint32_t)NW;  // dummy slot
        s_perm[addrw] = rv[k];
      }
    }
    __builtin_amdgcn_sched_barrier(0);
  }

  // ---- emission (post-rotation state = perms[T]) ----
  if (T >= BURN && (T - BURN) % SSTRIDE == 0) {
    asm volatile("s_waitcnt lgkmcnt(0)" ::: "memory");
    __builtin_amdgcn_sched_barrier(0);
    int row = (T - BURN) / SSTRIDE;
    int* orow = out + (size_t)row * NW;
    #pragma unroll
    for (int k = 0; k < 16; ++k) {
      uint4 wv = *(const uint4*)&s_perm[k * 256 + (int)lane * 4];
      *(uint4*)&orow[k * 256 + (int)lane * 4] = wv;
    }
  }

  // ---- shift proposal slots ----
  Plo[0] = Plo[1]; Phi[0] = Phi[1]; Psh[0] = Psh[1]; Plg[0] = Plg[1];
  Plo[1] = Plo[2]; Phi[1] = Phi[2]; Psh[1] = Psh[2]; Plg[1] = Plg[2];
  Plo[2] = Plo[3]; Phi[2] = Phi[3]; Psh[2] = Psh[3]; Plg[2] = Plg[3];
  accp = acc;
}

__global__ __launch_bounds__(NTHR)
void TwoOptMCMC_86148454023515_kernel(const float* __restrict__ bigram,
                                      const float* __restrict__ startw,
                                      const float* __restrict__ endw,
                                      int* __restrict__ out,
                                      const uint4* __restrict__ gprop) {
  __shared__ __align__(16) uint32_t s_perm[NW + 4];   // +dummy write slot
  __shared__ unsigned long long     s_comp[NW];       // init sort only
  __shared__ uint32_t               s_plohi[CH + 4];
  __shared__ uint32_t               s_psh[CH + 4];
  __shared__ float                  s_plg[CH + 4];

  const int tid = threadIdx.x;
  K2 kinit  = tf(0u, 42u, 0u, 0u);
  K2 kchain = tf(0u, 42u, 0u, 1u);

  // ---- initial permutation: 2-round stable-sort shuffle (256 threads) ----
  for (int i = tid; i < NW; i += NTHR) s_perm[i] = (uint32_t)i;
  __syncthreads();
  K2 kc = kinit;
  for (int rnd = 0; rnd < 2; ++rnd) {
    K2 knext = tf(kc.a, kc.b, 0u, 0u);
    K2 ksub  = tf(kc.a, kc.b, 0u, 1u);
    for (int i = tid; i < NW; i += NTHR) {
      K2 r = tf(ksub.a, ksub.b, 0u, (uint32_t)i);
      uint32_t sk = r.a ^ r.b;
      s_comp[i] = ((unsigned long long)sk << 24) |
                  ((unsigned long long)(uint32_t)i << 12) |
                  (unsigned long long)s_perm[i];
    }
    __syncthreads();
    for (int k = 2; k <= NW; k <<= 1) {
      for (int j = k >> 1; j > 0; j >>= 1) {
        for (int i = tid; i < NW; i += NTHR) {
          int ixj = i ^ j;
          if (ixj > i) {
            unsigned long long va = s_comp[i], vb = s_comp[ixj];
            bool up = ((i & k) == 0);
            if ((va > vb) == up) { s_comp[i] = vb; s_comp[ixj] = va; }
          }
        }
        __syncthreads();
      }
    }
    for (int i = tid; i < NW; i += NTHR) s_perm[i] = (uint32_t)(s_comp[i] & 0xFFFull);
    __syncthreads();
    kc = knext;
  }

  if (tid >= 64) return;            // single wave from here on; no barriers below
  const uint32_t lane = (uint32_t)tid;

#define REFILL(T0) do { \
    for (int i = (int)lane; i < CH + 3; i += 64) { \
      int tq = (T0) + i; \
      uint32_t lohi, shv; float lg; \
      if (tq < TSTEPS) { \
        if (gprop) { uint4 rr = gprop[tq]; lohi = rr.x; shv = rr.y; lg = __uint_as_float(rr.z); } \
        else { make_prop(kchain.a, kchain.b, tq, lohi, shv, lg); } \
      } else { lohi = 0u | (2u << 16); shv = 1u; lg = 0.f; } \
      s_plohi[i] = lohi; s_psh[i] = shv; s_plg[i] = lg; \
    } \
    asm volatile("s_waitcnt lgkmcnt(0)" ::: "memory"); \
    __builtin_amdgcn_sched_barrier(0); \
  } while (0)

  REFILL(0);

  uint32_t Plo[4], Phi[4], Psh[4]; float Plg[4];
  #pragma unroll
  for (int s = 0; s < 3; ++s) {
    uint32_t lh = __builtin_amdgcn_readfirstlane(s_plohi[s]);
    Plo[s] = lh & 0xFFFFu; Phi[s] = lh >> 16;
    Psh[s] = __builtin_amdgcn_readfirstlane(s_psh[s]);
    Plg[s] = __uint_as_float(__builtin_amdgcn_readfirstlane(__float_as_uint(s_plg[s])));
  }
  Plo[3] = 0; Phi[3] = 2; Psh[3] = 1; Plg[3] = 0.f;

  float vR[6], vA[6], wR[6], wA[6];
  bool accp = false;

  // prologue: loads for t=0 (direct from P_0) -> vR/vA (consumed at step 0)
  {
    uint32_t lo2 = Plo[0], hi2 = Phi[0], sh2 = Psh[0];
    uint32_t g0 = lo2, g1 = lo2 + sh2, g2 = g1 - 1u, g3 = hi2 - 1u;
    uint32_t g4 = (lo2 > 0u) ? lo2 - 1u : 0u;
    uint32_t g5 = (hi2 < (uint32_t)NW) ? hi2 : 0u;
    uint32_t Q0 = s_perm[g0], Q1 = s_perm[g1], Q2 = s_perm[g2];
    uint32_t Q3 = s_perm[g3], Q4 = s_perm[g4], Q5 = s_perm[g5];
    issue6(vR, Q0, Q1, Q2, Q3, Q4, Q5, lo2, hi2, bigram, startw, endw);
    issue6(vA, Q0, Q1, Q2, Q3, Q4, Q5, lo2, hi2, bigram, startw, endw);
  }
  // prologue: loads for t=1 (both acc_0 variants) -> wR/wA (consumed at step 1)
  {
    uint32_t lo2 = Plo[1], hi2 = Phi[1], sh2 = Psh[1];
    uint32_t g0 = lo2, g1 = lo2 + sh2, g2 = g1 - 1u, g3 = hi2 - 1u;
    uint32_t g4 = (lo2 > 0u) ? lo2 - 1u : 0u;
    uint32_t g5 = (hi2 < (uint32_t)NW) ? hi2 : 0u;
    uint32_t lo0 = Plo[0], sp0 = Phi[0] - Plo[0], sh0 = Psh[0];
    uint32_t z0 = smap2(g0, lo0, sp0, sh0), z1 = smap2(g1, lo0, sp0, sh0);
    uint32_t z2 = smap2(g2, lo0, sp0, sh0), z3 = smap2(g3, lo0, sp0, sh0);
    uint32_t z4 = smap2(g4, lo0, sp0, sh0), z5 = smap2(g5, lo0, sp0, sh0);
    uint32_t QR0 = s_perm[g0], QR1 = s_perm[g1], QR2 = s_perm[g2];
    uint32_t QR3 = s_perm[g3], QR4 = s_perm[g4], QR5 = s_perm[g5];
    uint32_t QA0 = s_perm[z0], QA1 = s_perm[z1], QA2 = s_perm[z2];
    uint32_t QA3 = s_perm[z3], QA4 = s_perm[z4], QA5 = s_perm[z5];
    issue6(wR, QR0, QR1, QR2, QR3, QR4, QR5, lo2, hi2, bigram, startw, endw);
    issue6(wA, QA0, QA1, QA2, QA3, QA4, QA5, lo2, hi2, bigram, startw, endw);
  }

  for (int t0 = 0; t0 < TSTEPS; t0 += CH) {
    if (t0 > 0) REFILL(t0);
    int nch = (TSTEPS - t0 < CH) ? (TSTEPS - t0) : CH;  // always even here
    for (int tt = 0; tt < nch; tt += 2) {
      step_body(t0 + tt,     tt,     lane, accp, Plo, Phi, Psh, Plg,
                vR, vA, s_perm, s_plohi, s_psh, s_plg,
                bigram, startw, endw, out);
      step_body(t0 + tt + 1, tt + 1, lane, accp, Plo, Phi, Psh, Plg,
                wR, wA, s_perm, s_plohi, s_psh, s_plg,
                bigram, startw, endw, out);
    }
  }
#undef REFILL
}

extern "C" void kernel_launch(void* const* d_in, const int* in_sizes, int n_in,
                              void* d_out, int out_size, void* d_ws, size_t ws_size,
                              hipStream_t stream) {
  (void)in_sizes; (void)n_in; (void)out_size;
  const float* bigram = (const float*)d_in[1];
  const float* startw = (const float*)d_in[2];
  const float* endw   = (const float*)d_in[3];
  int* out = (int*)d_out;
  uint4* gprop = nullptr;
  if (ws_size >= (size_t)TSTEPS * 16) {
    gprop = (uint4*)d_ws;
    hipLaunchKernelGGL(prop_kernel, dim3((TSTEPS + 255) / 256), dim3(256), 0, stream, gprop);
  }
  hipLaunchKernelGGL(TwoOptMCMC_86148454023515_kernel, dim3(1), dim3(NTHR), 0, stream,
                     bigram, startw, endw, out, gprop);
}